// Round 7
// baseline (414.363 us; speedup 1.0000x reference)
//
#include <hip/hip_runtime.h>
#include <stdint.h>

#define MDIM 4096
#define KDIM 4096
#define NDIM 11008
#define KP   (KDIM/8)   // 512 packed int32 per N-row
#define NKT  (KDIM/64)  // 64 K-steps of BK=64

typedef float  f32x4   __attribute__((ext_vector_type(4)));
typedef float  f32x16  __attribute__((ext_vector_type(16)));
typedef __bf16 bf16x8  __attribute__((ext_vector_type(8)));
typedef unsigned short u16x8 __attribute__((ext_vector_type(8)));

// RNE f32 -> bf16 bits (matches jax astype(bf16) for non-NaN inputs)
__device__ __forceinline__ unsigned short f2bf(float f) {
  uint32_t u = __builtin_bit_cast(uint32_t, f);
  u += 0x7FFFu + ((u >> 16) & 1u);
  return (unsigned short)(u >> 16);
}
__device__ __forceinline__ float bf2f(unsigned short h) {
  return __builtin_bit_cast(float, (uint32_t)h << 16);
}
__device__ __forceinline__ float bf16r(float f) { return bf2f(f2bf(f)); }

// async global -> LDS, 16B per lane, wave-uniform LDS base + lane*16
__device__ __forceinline__ void lds16(const void* g, void* l) {
  __builtin_amdgcn_global_load_lds(
      (const __attribute__((address_space(1))) unsigned int*)g,
      (__attribute__((address_space(3))) unsigned int*)l, 16, 0, 0);
}

// ---------------- pre-pass 1: dequant packed int4 -> bf16 W[N][K] -----------
__global__ __launch_bounds__(256) void dequant_w_kernel(
    const uint32_t* __restrict__ wq, const float* __restrict__ scales,
    const float* __restrict__ zeros, u16x8* __restrict__ Wbf) {
  int idx = blockIdx.x * 256 + threadIdx.x;      // [0, N*KP)
  int n = idx >> 9;                              // idx / 512
  float s = bf16r(scales[n]);
  float z = bf16r(zeros[n]);
  uint32_t w = wq[idx];
  u16x8 v;
#pragma unroll
  for (int j = 0; j < 8; ++j) {
    float qf = (float)((w >> (4 * j)) & 0xF);
    float t  = bf16r(qf * s);                    // bf16 mul rounding
    v[j] = f2bf(t + z);                          // bf16 add rounding
  }
  Wbf[idx] = v;
}

// ---------------- pre-pass 2: x f32 -> bf16 ---------------------------------
__global__ __launch_bounds__(256) void convert_x_kernel(
    const float4* __restrict__ x, u16x8* __restrict__ Xbf) {
  int idx = blockIdx.x * 256 + threadIdx.x;
  float4 a = x[2 * idx], b = x[2 * idx + 1];
  u16x8 v;
  v[0] = f2bf(a.x); v[1] = f2bf(a.y); v[2] = f2bf(a.z); v[3] = f2bf(a.w);
  v[4] = f2bf(b.x); v[5] = f2bf(b.y); v[6] = f2bf(b.z); v[7] = f2bf(b.w);
  Xbf[idx] = v;
}

// ---------------- main GEMM: 256x256, BK=64, 8 waves, 32x32x16, 2-phase -----
// Round-6 addressing (0-conflict proven) with phases merged 4 -> 2 per K-tile:
// each phase = {READ12 (both ks16 of one K-half) | STAGE 4 lds16 (A+B of one
// half-tile) | counted vmcnt | BAR | lgkm0 | 16 MFMA | BAR}. Barriers per tile
// 8 -> 4. Rationale: r4 (read prefetch) was NEUTRAL => reads are off the
// critical path; residual ~2400 cyc/tile is barrier/stage/vmcnt overhead
// (m233). Halving barrier count attacks that term directly.
// Ring: slot(T,h) = (2T+h)&3, A ring 4x16KB at 0, B ring at +64KB.
// vmcnt trace (4 loads/phase): pre-wait pending at any phase = 12 ->
// VMWAIT(8) retires the loads staged 2 phases earlier = exactly the slot
// first read 1 phase later (always after this phase's closing BAR). Tail:
// T=62 phB VMWAIT(4), T=63 phA VMWAIT(0).
__global__ __launch_bounds__(512, 2) void gemm256_kernel(
    const unsigned short* __restrict__ Abf,
    const unsigned short* __restrict__ Bbf,
    const float* __restrict__ bias, float* __restrict__ out) {
  __shared__ __align__(16) char smem[131072];

  const int tid  = threadIdx.x;
  const int lane = tid & 63;
  const int wave = tid >> 6;     // 0..7
  const int wm   = wave >> 2;    // 0..1 : M half (128 rows)
  const int wn   = wave & 3;     // 0..3 : N quarter (64 cols)

  // XCD-aware bijective swizzle: 688 = 8 * 86 blocks.
  const int b   = blockIdx.x;
  const int swz = (b & 7) * 86 + (b >> 3);
  const int mt  = swz / 43;
  const int nt  = swz - mt * 43;
  const int bm0 = mt * 256, bn0 = nt * 256;

  // staging: inverse st_16x32 permutation on the SOURCE (round-1 verified).
  // Odd subtiles store the two 16B k-slots swapped (source scol^8) — the
  // round-6 bank-balance fix.
  const int lp   = (lane >= 32) ? (lane ^ 2) : lane;
  const int srow = lp >> 2;        // 0..15
  const int scol = (lp & 3) << 3;  // 0,8,16,24 (bf16 elems)
  const unsigned short* aR  = Abf + (size_t)(bm0 + wave * 32 + srow) * KDIM + scol;
  const unsigned short* aR2 = Abf + (size_t)(bm0 + wave * 32 + 16 + srow) * KDIM + (scol ^ 8);
  const unsigned short* bR  = Bbf + (size_t)(bn0 + wave * 32 + srow) * KDIM + scol;
  const unsigned short* bR2 = Bbf + (size_t)(bn0 + wave * 32 + 16 + srow) * KDIM + (scol ^ 8);

  // 32x32x16 fragment read offset (ks16=0); ks16=1 address = this ^ 32.
  // byte = sub*1024 + r15*64 + (h*16 ^ sub*16) + swzb*32 — bank-quad class
  // 4*(r15&1) + ((h^sub) ^ 2*swzb): balanced per 16-lane group (r6: 0 confl).
  const int r31  = lane & 31;
  const int sub  = r31 >> 4;
  const int r15  = r31 & 15;
  const int kb   = (lane >> 5) << 4;        // 0 or 16 bytes
  const int swzb = (r15 >> 3) & 1;          // st_16x32: flip bit5 when row bit3
  const int rd0  = sub * 1024 + r15 * 64 + (kb ^ (sub << 4)) + swzb * 32;
  const int rd1  = rd0 ^ 32;

  const int aoffc = wm * 8192;          // wm*8 subtiles (128 rows)
  const int boffc = 65536 + wn * 4096;  // B ring + wn*4 subtiles (64 rows)

  f32x16 acc[4][2];
#pragma unroll
  for (int i = 0; i < 4; ++i)
#pragma unroll
    for (int j = 0; j < 2; ++j)
#pragma unroll
      for (int r = 0; r < 16; ++r) acc[i][j][r] = 0.f;

  bf16x8 Af[2][4], Bf[2][2];  // [ks16][frag] — all indices compile-time

// stage BOTH operands' subtile-pair for K-half (tile,ks) into slot
#define STAGE_FULL(tile, ks, slot)                                          \
  do {                                                                      \
    const size_t ko_ = (size_t)((tile) * 64 + (ks) * 32);                   \
    char* dA_ = smem + ((slot) << 14) + wave * 2048;                        \
    char* dB_ = dA_ + 65536;                                                \
    lds16(aR  + ko_, dA_);                                                  \
    lds16(aR2 + ko_, dA_ + 1024);                                           \
    lds16(bR  + ko_, dB_);                                                  \
    lds16(bR2 + ko_, dB_ + 1024);                                           \
  } while (0)

#define READ12(slotbase)                                                    \
  do {                                                                      \
    _Pragma("unroll") for (int ks = 0; ks < 2; ++ks) {                      \
      const int ro_ = ks ? rd1 : rd0;                                       \
      _Pragma("unroll") for (int mf = 0; mf < 4; ++mf)                      \
          Af[ks][mf] = *(const bf16x8*)(smem + aoffc + (slotbase) +         \
                                        mf * 2048 + ro_);                   \
      _Pragma("unroll") for (int nf = 0; nf < 2; ++nf)                      \
          Bf[ks][nf] = *(const bf16x8*)(smem + boffc + (slotbase) +         \
                                        nf * 2048 + ro_);                   \
    }                                                                       \
  } while (0)

#define MFMA16()                                                            \
  __builtin_amdgcn_s_setprio(1);                                            \
  _Pragma("unroll") for (int ks = 0; ks < 2; ++ks)                          \
      _Pragma("unroll") for (int mf = 0; mf < 4; ++mf)                      \
          _Pragma("unroll") for (int nf = 0; nf < 2; ++nf)                  \
              acc[mf][nf] = __builtin_amdgcn_mfma_f32_32x32x16_bf16(        \
                  Af[ks][mf], Bf[ks][nf], acc[mf][nf], 0, 0, 0);            \
  __builtin_amdgcn_s_setprio(0);

#define BAR                                                                 \
  __builtin_amdgcn_s_barrier();                                             \
  __builtin_amdgcn_sched_barrier(0);

#define SB0 __builtin_amdgcn_sched_barrier(0);

#define LGKM0                                                               \
  asm volatile("s_waitcnt lgkmcnt(0)" ::: "memory");                        \
  __builtin_amdgcn_sched_barrier(0);

#define VMWAIT(N) asm volatile("s_waitcnt vmcnt(" #N ")" ::: "memory")

  // TILE: phase A consumes slot S0s = (T,h0); phase B consumes S1s = (T,h1).
  // Stage: phA -> (T+1,h1) into SN1s; phB -> (T+2,h0) into S0s (recycled —
  // last reads of S0s completed at phA's LGKM0, ordered by phA's closing BAR).
#define TILE(T, S0s, S1s, SN1s, NSTG, VMA, VMB)                             \
  do {                                                                      \
    READ12((S0s) << 14);                                                    \
    if ((NSTG) >= 1) STAGE_FULL((T) + 1, 1, SN1s);                          \
    VMA;                                                                    \
    SB0; BAR; LGKM0; MFMA16(); BAR;                                         \
    READ12((S1s) << 14);                                                    \
    if ((NSTG) >= 2) STAGE_FULL((T) + 2, 0, S0s);                           \
    VMB;                                                                    \
    SB0; BAR; LGKM0; MFMA16(); BAR;                                         \
  } while (0)

  // prologue: (0,h0)->s0, (0,h1)->s1, (1,h0)->s2 = 12 loads; retire first 4
  STAGE_FULL(0, 0, 0);
  STAGE_FULL(0, 1, 1);
  STAGE_FULL(1, 0, 2);
  VMWAIT(8);
  BAR;

  for (int tt = 0; tt < 62; tt += 2) {
    TILE(tt,     0, 1, 3, 2, VMWAIT(8), VMWAIT(8));
    TILE(tt + 1, 2, 3, 1, 2, VMWAIT(8), VMWAIT(8));
  }
  // T=62: stage only (63,h1); T=63: no staging, drain
  TILE(62, 0, 1, 3, 1, VMWAIT(8), VMWAIT(4));
  TILE(63, 2, 3, 1, 0, VMWAIT(0), (void)0);

#undef TILE
#undef VMWAIT
#undef LGKM0
#undef SB0
#undef BAR
#undef MFMA16
#undef READ12
#undef STAGE_FULL

  // epilogue: 32x32 C/D layout: col = lane&31,
  // row = (reg&3) + 8*(reg>>2) + 4*(lane>>5)   [m74/m101 verified]
  const int colv = bn0 + wn * 64 + (lane & 31);
  const int rowb = bm0 + wm * 128 + ((lane >> 5) << 2);
  float bv[2];
  bv[0] = bias[colv];
  bv[1] = bias[colv + 32];
#pragma unroll
  for (int mf = 0; mf < 4; ++mf)
#pragma unroll
    for (int nf = 0; nf < 2; ++nf)
#pragma unroll
      for (int reg = 0; reg < 16; ++reg) {
        int row = rowb + mf * 32 + (reg & 3) + ((reg >> 2) << 3);
        out[(size_t)row * NDIM + colv + nf * 32] = acc[mf][nf][reg] + bv[nf];
      }
}

// ---------------- fallback fused 128x128 kernel (ws too small) --------------
__global__ __launch_bounds__(256, 3) void gemm_fused_kernel(
    const float* __restrict__ x, const uint32_t* __restrict__ wq,
    const float* __restrict__ scales, const float* __restrict__ zeros,
    const float* __restrict__ bias, float* __restrict__ out) {
  __shared__ __align__(16) char smem[2 * 128 * 64 * 2];
  char* As = smem;
  char* Bs = smem + 16384;

  const int tid  = threadIdx.x;
  const int lane = tid & 63;
  const int wave = tid >> 6;
  const int wm = wave >> 1, wn = wave & 1;

  const int b   = blockIdx.x;
  const int swz = (b & 7) * 344 + (b >> 3);
  const int mt  = swz / 86;
  const int nt  = swz - mt * 86;
  const int bm0 = mt * 128, bn0 = nt * 128;

  f32x4 acc[4][4];
#pragma unroll
  for (int i = 0; i < 4; ++i)
#pragma unroll
    for (int j = 0; j < 4; ++j) acc[i][j] = (f32x4){0.f, 0.f, 0.f, 0.f};

  const int base_a = ((wm * 64 + (lane & 15)) << 7) + ((lane >> 4) << 4);
  const int base_b = ((wn * 64 + (lane & 15)) << 7) + ((lane >> 4) << 4);

  float sv[4], zv[4];
#pragma unroll
  for (int it = 0; it < 4; ++it) {
    int r = bn0 + it * 32 + (tid >> 3);
    sv[it] = bf16r(scales[r]);
    zv[it] = bf16r(zeros[r]);
  }

  for (int kt = 0; kt < KDIM / 64; ++kt) {
    const int k0 = kt * 64;
    __syncthreads();
#pragma unroll
    for (int it = 0; it < 4; ++it) {
      int ch = it * 256 + tid;
      int row = ch >> 3, c8 = ch & 7;
      const float* src = x + (size_t)(bm0 + row) * KDIM + k0 + c8 * 8;
      float4 f0 = *(const float4*)src;
      float4 f1 = *(const float4*)(src + 4);
      u16x8 v;
      v[0] = f2bf(f0.x); v[1] = f2bf(f0.y); v[2] = f2bf(f0.z); v[3] = f2bf(f0.w);
      v[4] = f2bf(f1.x); v[5] = f2bf(f1.y); v[6] = f2bf(f1.z); v[7] = f2bf(f1.w);
      *(u16x8*)(As + row * 128 + c8 * 16) = v;
    }
#pragma unroll
    for (int it = 0; it < 4; ++it) {
      int ch = it * 256 + tid;
      int row = ch >> 3, kp = ch & 7;
      uint32_t w = wq[(size_t)(bn0 + row) * KP + kt * 8 + kp];
      float s = sv[it], z = zv[it];
      u16x8 v;
#pragma unroll
      for (int j = 0; j < 8; ++j) {
        float qf = (float)((w >> (4 * j)) & 0xF);
        float t  = bf16r(qf * s);
        v[j] = f2bf(t + z);
      }
      *(u16x8*)(Bs + row * 128 + kp * 16) = v;
    }
    __syncthreads();
#pragma unroll
    for (int ks = 0; ks < 2; ++ks) {
      bf16x8 af[4], bf[4];
#pragma unroll
      for (int i = 0; i < 4; ++i)
        af[i] = *(const bf16x8*)(As + base_a + i * 2048 + ks * 64);
#pragma unroll
      for (int j = 0; j < 4; ++j)
        bf[j] = *(const bf16x8*)(Bs + base_b + j * 2048 + ks * 64);
#pragma unroll
      for (int i = 0; i < 4; ++i)
#pragma unroll
        for (int j = 0; j < 4; ++j)
          acc[i][j] = __builtin_amdgcn_mfma_f32_16x16x32_bf16(af[i], bf[j],
                                                              acc[i][j], 0, 0, 0);
    }
  }

  const int colbase = bn0 + wn * 64 + (lane & 15);
  const int rowbase = bm0 + wm * 64 + ((lane >> 4) << 2);
  float bv[4];
#pragma unroll
  for (int j = 0; j < 4; ++j) bv[j] = bias[colbase + j * 16];
#pragma unroll
  for (int i = 0; i < 4; ++i) {
#pragma unroll
    for (int j = 0; j < 4; ++j) {
      size_t base = (size_t)(rowbase + i * 16) * NDIM + colbase + j * 16;
#pragma unroll
      for (int r = 0; r < 4; ++r)
        out[base + (size_t)r * NDIM] = acc[i][j][r] + bv[j];
    }
  }
}

extern "C" void kernel_launch(void* const* d_in, const int* in_sizes, int n_in,
                              void* d_out, int out_size, void* d_ws, size_t ws_size,
                              hipStream_t stream) {
  const float*    x      = (const float*)d_in[0];
  const uint32_t* wq     = (const uint32_t*)d_in[1];
  const float*    scales = (const float*)d_in[2];
  const float*    zeros  = (const float*)d_in[3];
  const float*    bias   = (const float*)d_in[4];
  float*          out    = (float*)d_out;

  const size_t needW = (size_t)NDIM * KDIM * 2;  // 90,177,536 B
  const size_t needX = (size_t)MDIM * KDIM * 2;  // 33,554,432 B

  if (ws_size >= needW + needX) {
    unsigned short* Wbf = (unsigned short*)d_ws;
    unsigned short* Xbf = (unsigned short*)((char*)d_ws + needW);
    dequant_w_kernel<<<(NDIM * KP) / 256, 256, 0, stream>>>(wq, scales, zeros,
                                                            (u16x8*)Wbf);
    convert_x_kernel<<<(MDIM * KDIM / 8) / 256, 256, 0, stream>>>(
        (const float4*)x, (u16x8*)Xbf);
    gemm256_kernel<<<688, 512, 0, stream>>>(Xbf, Wbf, bias, out);
  } else {
    gemm_fused_kernel<<<2752, 256, 0, stream>>>(x, wq, scales, zeros, bias, out);
  }
}

// Round 8
// 403.481 us; speedup vs baseline: 1.0270x; 1.0270x over previous
//
#include <hip/hip_runtime.h>
#include <stdint.h>

#define MDIM 4096
#define KDIM 4096
#define NDIM 11008
#define KP   (KDIM/8)   // 512 packed int32 per N-row
#define NKT  (KDIM/64)  // 64 K-steps of BK=64

typedef float  f32x4   __attribute__((ext_vector_type(4)));
typedef float  f32x16  __attribute__((ext_vector_type(16)));
typedef __bf16 bf16x8  __attribute__((ext_vector_type(8)));
typedef unsigned short u16x8 __attribute__((ext_vector_type(8)));

// RNE f32 -> bf16 bits (matches jax astype(bf16) for non-NaN inputs)
__device__ __forceinline__ unsigned short f2bf(float f) {
  uint32_t u = __builtin_bit_cast(uint32_t, f);
  u += 0x7FFFu + ((u >> 16) & 1u);
  return (unsigned short)(u >> 16);
}
__device__ __forceinline__ float bf2f(unsigned short h) {
  return __builtin_bit_cast(float, (uint32_t)h << 16);
}
__device__ __forceinline__ float bf16r(float f) { return bf2f(f2bf(f)); }

// async global -> LDS, 16B per lane, wave-uniform LDS base + lane*16
__device__ __forceinline__ void lds16(const void* g, void* l) {
  __builtin_amdgcn_global_load_lds(
      (const __attribute__((address_space(1))) unsigned int*)g,
      (__attribute__((address_space(3))) unsigned int*)l, 16, 0, 0);
}

// ---------------- pre-pass 1: dequant packed int4 -> bf16 W[N][K] -----------
__global__ __launch_bounds__(256) void dequant_w_kernel(
    const uint32_t* __restrict__ wq, const float* __restrict__ scales,
    const float* __restrict__ zeros, u16x8* __restrict__ Wbf) {
  int idx = blockIdx.x * 256 + threadIdx.x;      // [0, N*KP)
  int n = idx >> 9;                              // idx / 512
  float s = bf16r(scales[n]);
  float z = bf16r(zeros[n]);
  uint32_t w = wq[idx];
  u16x8 v;
#pragma unroll
  for (int j = 0; j < 8; ++j) {
    float qf = (float)((w >> (4 * j)) & 0xF);
    float t  = bf16r(qf * s);                    // bf16 mul rounding
    v[j] = f2bf(t + z);                          // bf16 add rounding
  }
  Wbf[idx] = v;
}

// ---------------- pre-pass 2: x f32 -> bf16 ---------------------------------
__global__ __launch_bounds__(256) void convert_x_kernel(
    const float4* __restrict__ x, u16x8* __restrict__ Xbf) {
  int idx = blockIdx.x * 256 + threadIdx.x;
  float4 a = x[2 * idx], b = x[2 * idx + 1];
  u16x8 v;
  v[0] = f2bf(a.x); v[1] = f2bf(a.y); v[2] = f2bf(a.z); v[3] = f2bf(a.w);
  v[4] = f2bf(b.x); v[5] = f2bf(b.y); v[6] = f2bf(b.z); v[7] = f2bf(b.w);
  Xbf[idx] = v;
}

// ---------------- main GEMM: 256x256, BK=64, 8 waves, 32x32x16, 4-phase -----
// EXACT round-6 frame (ring, addressing, vmcnt trace — all passing/0-conflict)
// with the scheduling pins REMOVED: no explicit lgkmcnt(0), no standalone
// sched_barrier(0). The MFMA's register dependence on the ds_read results
// forces the compiler's own fine-grained lgkmcnt (m97 asm evidence); rule #18
// applies only to inline-asm ds_reads, which these are not. Keep: BAR =
// s_barrier + sched_barrier(0) (guard against hoisting reads of a slot above
// the barrier that publishes other waves' lds16 writes), VMWAIT with memory
// clobber (blocks compiler motion of memory ops across it), setprio (T5).
// Hypothesis: r6's extra pins (m141: order-pinning defeats the scheduler)
// cost ~40 us and masked the 32x32x16 pipe-rate gain.
__global__ __launch_bounds__(512, 2) void gemm256_kernel(
    const unsigned short* __restrict__ Abf,
    const unsigned short* __restrict__ Bbf,
    const float* __restrict__ bias, float* __restrict__ out) {
  __shared__ __align__(16) char smem[131072];

  const int tid  = threadIdx.x;
  const int lane = tid & 63;
  const int wave = tid >> 6;     // 0..7
  const int wm   = wave >> 2;    // 0..1 : M half (128 rows)
  const int wn   = wave & 3;     // 0..3 : N quarter (64 cols)

  // XCD-aware bijective swizzle: 688 = 8 * 86 blocks.
  const int b   = blockIdx.x;
  const int swz = (b & 7) * 86 + (b >> 3);
  const int mt  = swz / 43;
  const int nt  = swz - mt * 43;
  const int bm0 = mt * 256, bn0 = nt * 256;

  // staging: inverse st_16x32 permutation on the SOURCE (round-1 verified).
  // Odd subtiles store the two 16B k-slots swapped (source scol^8) — the
  // round-6 bank-balance fix.
  const int lp   = (lane >= 32) ? (lane ^ 2) : lane;
  const int srow = lp >> 2;        // 0..15
  const int scol = (lp & 3) << 3;  // 0,8,16,24 (bf16 elems)
  const unsigned short* aR  = Abf + (size_t)(bm0 + wave * 32 + srow) * KDIM + scol;
  const unsigned short* aR2 = Abf + (size_t)(bm0 + wave * 32 + 16 + srow) * KDIM + (scol ^ 8);
  const unsigned short* bR  = Bbf + (size_t)(bn0 + wave * 32 + srow) * KDIM + scol;
  const unsigned short* bR2 = Bbf + (size_t)(bn0 + wave * 32 + 16 + srow) * KDIM + (scol ^ 8);

  // 32x32x16 fragment read offset (ks16=0); ks16=1 address = this ^ 32.
  // byte = sub*1024 + r15*64 + (h*16 ^ sub*16) + swzb*32 — bank-quad class
  // 4*(r15&1) + ((h^sub) ^ 2*swzb): balanced per 16-lane group (r6: 0 confl).
  const int r31  = lane & 31;
  const int sub  = r31 >> 4;
  const int r15  = r31 & 15;
  const int kb   = (lane >> 5) << 4;        // 0 or 16 bytes
  const int swzb = (r15 >> 3) & 1;          // st_16x32: flip bit5 when row bit3
  const int rd0  = sub * 1024 + r15 * 64 + (kb ^ (sub << 4)) + swzb * 32;
  const int rd1  = rd0 ^ 32;

  const int aoffc = wm * 8192;          // wm*8 subtiles (128 rows)
  const int boffc = 65536 + wn * 4096;  // B ring + wn*4 subtiles (64 rows)

  f32x16 acc[4][2];
#pragma unroll
  for (int i = 0; i < 4; ++i)
#pragma unroll
    for (int j = 0; j < 2; ++j)
#pragma unroll
      for (int r = 0; r < 16; ++r) acc[i][j][r] = 0.f;

  bf16x8 Af[4], Bf[2];

#define STAGE_HALF(R1, R2, ringoff, tile, ks, slot)                         \
  do {                                                                      \
    const size_t ko_ = (size_t)((tile) * 64 + (ks) * 32);                   \
    char* d_ = smem + (ringoff) + ((slot) << 14) + wave * 2048;             \
    lds16((R1) + ko_, d_);                                                  \
    lds16((R2) + ko_, d_ + 1024);                                           \
  } while (0)

#define READ6(slotbase, KS)                                                 \
  do {                                                                      \
    const int ro_ = (KS) ? rd1 : rd0;                                       \
    _Pragma("unroll") for (int mf = 0; mf < 4; ++mf)                        \
        Af[mf] = *(const bf16x8*)(smem + aoffc + (slotbase) +               \
                                  mf * 2048 + ro_);                         \
    _Pragma("unroll") for (int nf = 0; nf < 2; ++nf)                        \
        Bf[nf] = *(const bf16x8*)(smem + boffc + (slotbase) +               \
                                  nf * 2048 + ro_);                         \
  } while (0)

#define MFMA8()                                                             \
  __builtin_amdgcn_s_setprio(1);                                            \
  _Pragma("unroll") for (int mf = 0; mf < 4; ++mf)                          \
      _Pragma("unroll") for (int nf = 0; nf < 2; ++nf)                      \
          acc[mf][nf] = __builtin_amdgcn_mfma_f32_32x32x16_bf16(            \
              Af[mf], Bf[nf], acc[mf][nf], 0, 0, 0);                        \
  __builtin_amdgcn_s_setprio(0);

#define BAR                                                                 \
  __builtin_amdgcn_s_barrier();                                             \
  __builtin_amdgcn_sched_barrier(0);

#define VMWAIT(N) asm volatile("s_waitcnt vmcnt(" #N ")" ::: "memory")

  // One phase = one ks16 step: {READ6 | STAGE | [vmcnt] | BAR | 8x MFMA |
  // BAR}. Slot schedule identical to rounds 3-6 (traced): S0s/S1s = slots of
  // (T, ks-half0/1); SN1s = slot for (T+1,h1) staging; (T+2,h0) recycles into
  // S0s. VMWAIT(8) at p1 retires s1 for p2; at p3 retires next tile's s0.
#define TILE(T, S0s, S1s, SN1s, NSTG, VM1STMT, VM3STMT)                     \
  do {                                                                      \
    /* p0: ks16=0 (slot s0 low half) */                                     \
    READ6((S0s) << 14, 0);                                                  \
    if ((NSTG) >= 1) STAGE_HALF(aR, aR2, 0, (T) + 1, 1, SN1s);              \
    BAR; MFMA8(); BAR;                                                      \
    /* p1: ks16=1 */                                                        \
    READ6((S0s) << 14, 1);                                                  \
    if ((NSTG) >= 2) STAGE_HALF(bR, bR2, 65536, (T) + 1, 1, SN1s);          \
    VM1STMT;                                                                \
    BAR; MFMA8(); BAR;                                                      \
    /* p2: ks16=2 (slot s1 low half) */                                     \
    READ6((S1s) << 14, 0);                                                  \
    if ((NSTG) >= 3) STAGE_HALF(aR, aR2, 0, (T) + 2, 0, S0s);               \
    BAR; MFMA8(); BAR;                                                      \
    /* p3: ks16=3 */                                                        \
    READ6((S1s) << 14, 1);                                                  \
    if ((NSTG) >= 4) STAGE_HALF(bR, bR2, 65536, (T) + 2, 0, S0s);           \
    VM3STMT;                                                                \
    BAR; MFMA8(); BAR;                                                      \
  } while (0)

  // prologue: A0(0),B0(0),A1(0),B1(0),A0(1),B0(1) = 12 loads; wait first 4
  STAGE_HALF(aR, aR2, 0, 0, 0, 0);
  STAGE_HALF(bR, bR2, 65536, 0, 0, 0);
  STAGE_HALF(aR, aR2, 0, 0, 1, 1);
  STAGE_HALF(bR, bR2, 65536, 0, 1, 1);
  STAGE_HALF(aR, aR2, 0, 1, 0, 2);
  STAGE_HALF(bR, bR2, 65536, 1, 0, 2);
  VMWAIT(8);
  BAR;

  for (int tt = 0; tt < 62; tt += 2) {
    TILE(tt,     0, 1, 3, 4, VMWAIT(8), VMWAIT(8));
    TILE(tt + 1, 2, 3, 1, 4, VMWAIT(8), VMWAIT(8));
  }
  // t=62: stage only A1(63),B1(63); t=63: no staging, drain at p1
  TILE(62, 0, 1, 3, 2, VMWAIT(8), VMWAIT(4));
  TILE(63, 2, 3, 1, 0, VMWAIT(0), (void)0);

#undef TILE
#undef VMWAIT
#undef BAR
#undef MFMA8
#undef READ6
#undef STAGE_HALF

  // epilogue: 32x32 C/D layout: col = lane&31,
  // row = (reg&3) + 8*(reg>>2) + 4*(lane>>5)   [m74/m101 verified]
  const int colv = bn0 + wn * 64 + (lane & 31);
  const int rowb = bm0 + wm * 128 + ((lane >> 5) << 2);
  float bv[2];
  bv[0] = bias[colv];
  bv[1] = bias[colv + 32];
#pragma unroll
  for (int mf = 0; mf < 4; ++mf)
#pragma unroll
    for (int nf = 0; nf < 2; ++nf)
#pragma unroll
      for (int reg = 0; reg < 16; ++reg) {
        int row = rowb + mf * 32 + (reg & 3) + ((reg >> 2) << 3);
        out[(size_t)row * NDIM + colv + nf * 32] = acc[mf][nf][reg] + bv[nf];
      }
}

// ---------------- fallback fused 128x128 kernel (ws too small) --------------
__global__ __launch_bounds__(256, 3) void gemm_fused_kernel(
    const float* __restrict__ x, const uint32_t* __restrict__ wq,
    const float* __restrict__ scales, const float* __restrict__ zeros,
    const float* __restrict__ bias, float* __restrict__ out) {
  __shared__ __align__(16) char smem[2 * 128 * 64 * 2];
  char* As = smem;
  char* Bs = smem + 16384;

  const int tid  = threadIdx.x;
  const int lane = tid & 63;
  const int wave = tid >> 6;
  const int wm = wave >> 1, wn = wave & 1;

  const int b   = blockIdx.x;
  const int swz = (b & 7) * 344 + (b >> 3);
  const int mt  = swz / 86;
  const int nt  = swz - mt * 86;
  const int bm0 = mt * 128, bn0 = nt * 128;

  f32x4 acc[4][4];
#pragma unroll
  for (int i = 0; i < 4; ++i)
#pragma unroll
    for (int j = 0; j < 4; ++j) acc[i][j] = (f32x4){0.f, 0.f, 0.f, 0.f};

  const int base_a = ((wm * 64 + (lane & 15)) << 7) + ((lane >> 4) << 4);
  const int base_b = ((wn * 64 + (lane & 15)) << 7) + ((lane >> 4) << 4);

  float sv[4], zv[4];
#pragma unroll
  for (int it = 0; it < 4; ++it) {
    int r = bn0 + it * 32 + (tid >> 3);
    sv[it] = bf16r(scales[r]);
    zv[it] = bf16r(zeros[r]);
  }

  for (int kt = 0; kt < KDIM / 64; ++kt) {
    const int k0 = kt * 64;
    __syncthreads();
#pragma unroll
    for (int it = 0; it < 4; ++it) {
      int ch = it * 256 + tid;
      int row = ch >> 3, c8 = ch & 7;
      const float* src = x + (size_t)(bm0 + row) * KDIM + k0 + c8 * 8;
      float4 f0 = *(const float4*)src;
      float4 f1 = *(const float4*)(src + 4);
      u16x8 v;
      v[0] = f2bf(f0.x); v[1] = f2bf(f0.y); v[2] = f2bf(f0.z); v[3] = f2bf(f0.w);
      v[4] = f2bf(f1.x); v[5] = f2bf(f1.y); v[6] = f2bf(f1.z); v[7] = f2bf(f1.w);
      *(u16x8*)(As + row * 128 + c8 * 16) = v;
    }
#pragma unroll
    for (int it = 0; it < 4; ++it) {
      int ch = it * 256 + tid;
      int row = ch >> 3, kp = ch & 7;
      uint32_t w = wq[(size_t)(bn0 + row) * KP + kt * 8 + kp];
      float s = sv[it], z = zv[it];
      u16x8 v;
#pragma unroll
      for (int j = 0; j < 8; ++j) {
        float qf = (float)((w >> (4 * j)) & 0xF);
        float t  = bf16r(qf * s);
        v[j] = f2bf(t + z);
      }
      *(u16x8*)(Bs + row * 128 + kp * 16) = v;
    }
    __syncthreads();
#pragma unroll
    for (int ks = 0; ks < 2; ++ks) {
      bf16x8 af[4], bf[4];
#pragma unroll
      for (int i = 0; i < 4; ++i)
        af[i] = *(const bf16x8*)(As + base_a + i * 2048 + ks * 64);
#pragma unroll
      for (int j = 0; j < 4; ++j)
        bf[j] = *(const bf16x8*)(Bs + base_b + j * 2048 + ks * 64);
#pragma unroll
      for (int i = 0; i < 4; ++i)
#pragma unroll
        for (int j = 0; j < 4; ++j)
          acc[i][j] = __builtin_amdgcn_mfma_f32_16x16x32_bf16(af[i], bf[j],
                                                              acc[i][j], 0, 0, 0);
    }
  }

  const int colbase = bn0 + wn * 64 + (lane & 15);
  const int rowbase = bm0 + wm * 64 + ((lane >> 4) << 2);
  float bv[4];
#pragma unroll
  for (int j = 0; j < 4; ++j) bv[j] = bias[colbase + j * 16];
#pragma unroll
  for (int i = 0; i < 4; ++i) {
#pragma unroll
    for (int j = 0; j < 4; ++j) {
      size_t base = (size_t)(rowbase + i * 16) * NDIM + colbase + j * 16;
#pragma unroll
      for (int r = 0; r < 4; ++r)
        out[base + (size_t)r * NDIM] = acc[i][j][r] + bv[j];
    }
  }
}

extern "C" void kernel_launch(void* const* d_in, const int* in_sizes, int n_in,
                              void* d_out, int out_size, void* d_ws, size_t ws_size,
                              hipStream_t stream) {
  const float*    x      = (const float*)d_in[0];
  const uint32_t* wq     = (const uint32_t*)d_in[1];
  const float*    scales = (const float*)d_in[2];
  const float*    zeros  = (const float*)d_in[3];
  const float*    bias   = (const float*)d_in[4];
  float*          out    = (float*)d_out;

  const size_t needW = (size_t)NDIM * KDIM * 2;  // 90,177,536 B
  const size_t needX = (size_t)MDIM * KDIM * 2;  // 33,554,432 B

  if (ws_size >= needW + needX) {
    unsigned short* Wbf = (unsigned short*)d_ws;
    unsigned short* Xbf = (unsigned short*)((char*)d_ws + needW);
    dequant_w_kernel<<<(NDIM * KP) / 256, 256, 0, stream>>>(wq, scales, zeros,
                                                            (u16x8*)Wbf);
    convert_x_kernel<<<(MDIM * KDIM / 8) / 256, 256, 0, stream>>>(
        (const float4*)x, (u16x8*)Xbf);
    gemm256_kernel<<<688, 512, 0, stream>>>(Xbf, Wbf, bias, out);
  } else {
    gemm_fused_kernel<<<2752, 256, 0, stream>>>(x, wq, scales, zeros, bias, out);
  }
}

// Round 9
// 244.134 us; speedup vs baseline: 1.6973x; 1.6527x over previous
//
#include <hip/hip_runtime.h>
#include <stdint.h>

#define MDIM 4096
#define KDIM 4096
#define NDIM 11008
#define KP   (KDIM/8)    // 512 packed int32 per N-row
#define NKT2 (KDIM/128)  // 32 K-tiles of BK=128 (int8 path)

typedef float  f32x4   __attribute__((ext_vector_type(4)));
typedef __bf16 bf16x8  __attribute__((ext_vector_type(8)));
typedef unsigned short u16x8 __attribute__((ext_vector_type(8)));
typedef int    i32x4   __attribute__((ext_vector_type(4)));
typedef int    i32x16  __attribute__((ext_vector_type(16)));
typedef char   c8x8    __attribute__((ext_vector_type(8)));
typedef char   c8x16   __attribute__((ext_vector_type(16)));

// RNE f32 -> bf16 bits (matches jax astype(bf16) for non-NaN inputs)
__device__ __forceinline__ unsigned short f2bf(float f) {
  uint32_t u = __builtin_bit_cast(uint32_t, f);
  u += 0x7FFFu + ((u >> 16) & 1u);
  return (unsigned short)(u >> 16);
}
__device__ __forceinline__ float bf2f(unsigned short h) {
  return __builtin_bit_cast(float, (uint32_t)h << 16);
}
__device__ __forceinline__ float bf16r(float f) { return bf2f(f2bf(f)); }

// async global -> LDS, 16B per lane, wave-uniform LDS base + lane*16
__device__ __forceinline__ void lds16(const void* g, void* l) {
  __builtin_amdgcn_global_load_lds(
      (const __attribute__((address_space(1))) unsigned int*)g,
      (__attribute__((address_space(3))) unsigned int*)l, 16, 0, 0);
}

// ---------------- pre-pass 1: unpack int4 words -> int8 Q8[N][K] ------------
__global__ __launch_bounds__(256) void repack_q_kernel(
    const uint32_t* __restrict__ wq, c8x8* __restrict__ Q8) {
  int idx = blockIdx.x * 256 + threadIdx.x;   // [0, N*KP)
  uint32_t w = wq[idx];
  c8x8 v;
#pragma unroll
  for (int j = 0; j < 8; ++j) v[j] = (char)((w >> (4 * j)) & 0xF);
  Q8[idx] = v;
}

// ---------------- pre-pass 2: x f32 -> per-row int8 + delta + exact bf16 sum
// one block per row. x8 = round(bf16(x)/Delta), Delta = rowmax|bf16(x)|/127.
// xsum = exact f32 sum of bf16(x) (feeds the z-term with NO quant error).
__global__ __launch_bounds__(256) void quant_x_kernel(
    const float* __restrict__ x, c8x16* __restrict__ X8,
    float* __restrict__ delta, float* __restrict__ xsum) {
  __shared__ float red[256];
  const int row = blockIdx.x, t = threadIdx.x;
  const float4* xr = (const float4*)(x + (size_t)row * KDIM);
  float xb[16];
#pragma unroll
  for (int i = 0; i < 4; ++i) {
    float4 f = xr[t * 4 + i];
    xb[i * 4 + 0] = bf16r(f.x); xb[i * 4 + 1] = bf16r(f.y);
    xb[i * 4 + 2] = bf16r(f.z); xb[i * 4 + 3] = bf16r(f.w);
  }
  float mx = 0.f, sm = 0.f;
#pragma unroll
  for (int j = 0; j < 16; ++j) { mx = fmaxf(mx, fabsf(xb[j])); sm += xb[j]; }
  red[t] = mx; __syncthreads();
  for (int o = 128; o > 0; o >>= 1) {
    if (t < o) red[t] = fmaxf(red[t], red[t + o]);
    __syncthreads();
  }
  const float rmx = red[0];
  __syncthreads();
  red[t] = sm; __syncthreads();
  for (int o = 128; o > 0; o >>= 1) {
    if (t < o) red[t] += red[t + o];
    __syncthreads();
  }
  const float rsm = red[0];
  const float inv = (rmx > 0.f) ? 127.0f / rmx : 0.f;
  if (t == 0) {
    delta[row] = (rmx > 0.f) ? rmx / 127.0f : 0.f;
    xsum[row]  = rsm;
  }
  c8x16 q;
#pragma unroll
  for (int j = 0; j < 16; ++j) q[j] = (char)__float2int_rn(xb[j] * inv);
  X8[(size_t)row * 256 + t] = q;
}

// ---------------- main GEMM: 256x256, BK=128, 8 waves, i8 32x32x32, 4-phase -
// Same traced ring/vmcnt skeleton as round 8 (passing), halved tile count
// (32 K-tiles of BK=128). Slot = 16KB = one K-HALF (64 i8 k) of one operand
// (256 rows x 64B), 16 subtiles of 16r x 64B (1KB). A ring 4x16KB at 0,
// B ring at +64KB.
// Swizzle (paper-verified involution + bank balance): within a subtile the
// 16B chunk index stored at position c is kappa = c ^ (((row>>1)&1)<<1) ^ sub.
// Read addr = sub*1024 + r15*64 + s*32 + hk*16, then ^((r15&2)<<4) ^ (sub<<4)
// -> bank-quad class = {r15&1, s^(r15>>1), hk^sub}: 8 classes x 4 lanes per
// 32-lane window -> conflict-free. Staging realizes the inverse by permuting
// the per-lane GLOBAL chunk (linear LDS dest, rule #21).
__global__ __launch_bounds__(512, 2) void gemm256_i8_kernel(
    const char* __restrict__ A8, const char* __restrict__ Q8,
    const float* __restrict__ delta, const float* __restrict__ xsum,
    const float* __restrict__ scales, const float* __restrict__ zeros,
    const float* __restrict__ bias, float* __restrict__ out) {
  __shared__ __align__(16) char smem[131072];

  const int tid  = threadIdx.x;
  const int lane = tid & 63;
  const int wave = tid >> 6;     // 0..7
  const int wm   = wave >> 2;    // 0..1 : M half (128 rows)
  const int wn   = wave & 3;     // 0..3 : N quarter (64 cols)

  // XCD-aware bijective swizzle: 688 = 8 * 86 blocks.
  const int b   = blockIdx.x;
  const int swz = (b & 7) * 86 + (b >> 3);
  const int mt  = swz / 43;
  const int nt  = swz - mt * 43;
  const int bm0 = mt * 256, bn0 = nt * 256;

  // staging geometry: lane l writes subtile bytes [l*16, l*16+16):
  // row srow = l>>2, stored chunk schunk = l&3; source global chunk =
  // schunk ^ ((srow>>1)&1)*2 (^1 for the odd subtile).
  const int srow   = lane >> 2;
  const int schunk = lane & 3;
  const int perm0  = schunk ^ (((srow >> 1) & 1) << 1);
  const int perm1  = perm0 ^ 1;
  const char* aR  = A8 + (size_t)(bm0 + wave * 32 + srow) * KDIM + perm0 * 16;
  const char* aR2 = A8 + (size_t)(bm0 + wave * 32 + 16 + srow) * KDIM + perm1 * 16;
  const char* bR  = Q8 + (size_t)(bn0 + wave * 32 + srow) * KDIM + perm0 * 16;
  const char* bR2 = Q8 + (size_t)(bn0 + wave * 32 + 16 + srow) * KDIM + perm1 * 16;

  // fragment read offset for ks32 step s=0 (rd0) / s=1 (rd1 = rd0^32).
  const int r31 = lane & 31;
  const int sub = r31 >> 4;
  const int r15 = r31 & 15;
  const int hk  = lane >> 5;
  const int rd0 = sub * 1024 + r15 * 64 + ((hk ^ sub) << 4) + ((r15 & 2) << 4);
  const int rd1 = rd0 ^ 32;

  const int aoffc = wm * 8192;          // wm*8 subtiles (128 rows)
  const int boffc = 65536 + wn * 4096;  // B ring + wn*4 subtiles (64 rows)

  i32x16 acc[4][2];
#pragma unroll
  for (int i = 0; i < 4; ++i)
#pragma unroll
    for (int j = 0; j < 2; ++j)
#pragma unroll
      for (int r = 0; r < 16; ++r) acc[i][j][r] = 0;

  i32x4 Af[4], Bf[2];

#define STAGE_A(tile, h, slot)                                              \
  do {                                                                      \
    const size_t ko_ = (size_t)((tile) * 128 + (h) * 64);                   \
    char* d_ = smem + ((slot) << 14) + wave * 2048;                         \
    lds16(aR + ko_, d_);                                                    \
    lds16(aR2 + ko_, d_ + 1024);                                            \
  } while (0)

#define STAGE_B(tile, h, slot)                                              \
  do {                                                                      \
    const size_t ko_ = (size_t)((tile) * 128 + (h) * 64);                   \
    char* d_ = smem + 65536 + ((slot) << 14) + wave * 2048;                 \
    lds16(bR + ko_, d_);                                                    \
    lds16(bR2 + ko_, d_ + 1024);                                            \
  } while (0)

#define READ6(slotbase, S)                                                  \
  do {                                                                      \
    const int ro_ = (S) ? rd1 : rd0;                                        \
    _Pragma("unroll") for (int mf = 0; mf < 4; ++mf)                        \
        Af[mf] = *(const i32x4*)(smem + aoffc + (slotbase) +                \
                                 mf * 2048 + ro_);                          \
    _Pragma("unroll") for (int nf = 0; nf < 2; ++nf)                        \
        Bf[nf] = *(const i32x4*)(smem + boffc + (slotbase) +                \
                                 nf * 2048 + ro_);                          \
  } while (0)

#define MFMA8()                                                             \
  __builtin_amdgcn_s_setprio(1);                                            \
  _Pragma("unroll") for (int mf = 0; mf < 4; ++mf)                          \
      _Pragma("unroll") for (int nf = 0; nf < 2; ++nf)                      \
          acc[mf][nf] = __builtin_amdgcn_mfma_i32_32x32x32_i8(              \
              Af[mf], Bf[nf], acc[mf][nf], 0, 0, 0);                        \
  __builtin_amdgcn_s_setprio(0);

#define BAR                                                                 \
  __builtin_amdgcn_s_barrier();                                             \
  __builtin_amdgcn_sched_barrier(0);

#define VMWAIT(N) asm volatile("s_waitcnt vmcnt(" #N ")" ::: "memory")

  // 4 phases/K-tile: (h0,s0),(h0,s1),(h1,s0),(h1,s1). Staging: p0 A(T+1,h1),
  // p1 B(T+1,h1) + VM, p2 A(T+2,h0)->S0s (recycle), p3 B(T+2,h0) + VM.
  // Identical slot/vmcnt schedule to round 8 (traced + passing).
#define TILE(T, S0s, S1s, SN1s, NSTG, VM1STMT, VM3STMT)                     \
  do {                                                                      \
    READ6((S0s) << 14, 0);                                                  \
    if ((NSTG) >= 1) STAGE_A((T) + 1, 1, SN1s);                             \
    BAR; MFMA8(); BAR;                                                      \
    READ6((S0s) << 14, 1);                                                  \
    if ((NSTG) >= 2) STAGE_B((T) + 1, 1, SN1s);                             \
    VM1STMT;                                                                \
    BAR; MFMA8(); BAR;                                                      \
    READ6((S1s) << 14, 0);                                                  \
    if ((NSTG) >= 3) STAGE_A((T) + 2, 0, S0s);                              \
    BAR; MFMA8(); BAR;                                                      \
    READ6((S1s) << 14, 1);                                                  \
    if ((NSTG) >= 4) STAGE_B((T) + 2, 0, S0s);                              \
    VM3STMT;                                                                \
    BAR; MFMA8(); BAR;                                                      \
  } while (0)

  // prologue: (0,h0)->s0, (0,h1)->s1, (1,h0)->s2 = 12 loads; retire first 4
  STAGE_A(0, 0, 0);
  STAGE_B(0, 0, 0);
  STAGE_A(0, 1, 1);
  STAGE_B(0, 1, 1);
  STAGE_A(1, 0, 2);
  STAGE_B(1, 0, 2);
  VMWAIT(8);
  BAR;

  for (int tt = 0; tt < 30; tt += 2) {
    TILE(tt,     0, 1, 3, 4, VMWAIT(8), VMWAIT(8));
    TILE(tt + 1, 2, 3, 1, 4, VMWAIT(8), VMWAIT(8));
  }
  // T=30: stage only (31,h1); T=31: no staging, drain
  TILE(30, 0, 1, 3, 2, VMWAIT(8), VMWAIT(4));
  TILE(31, 2, 3, 1, 0, VMWAIT(0), (void)0);

#undef TILE
#undef VMWAIT
#undef BAR
#undef MFMA8
#undef READ6
#undef STAGE_B
#undef STAGE_A

  // epilogue: C/D 32x32 layout col=lane&31, row=(reg&3)+8*(reg>>2)+4*(lane>>5)
  // out = acc * (Delta_m * bf16(s_n)) + bf16(z_n) * xsum_m + bias_n
  const int colv = bn0 + wn * 64 + (lane & 31);
  const int rowb = bm0 + wm * 128 + ((lane >> 5) << 2);
  float sb[2], zb[2], bv[2];
#pragma unroll
  for (int nf = 0; nf < 2; ++nf) {
    sb[nf] = bf16r(scales[colv + nf * 32]);
    zb[nf] = bf16r(zeros[colv + nf * 32]);
    bv[nf] = bias[colv + nf * 32];
  }
#pragma unroll
  for (int mf = 0; mf < 4; ++mf)
#pragma unroll
    for (int reg = 0; reg < 16; ++reg) {
      const int row = rowb + mf * 32 + (reg & 3) + ((reg >> 2) << 3);
      const float dm = delta[row];
      const float xm = xsum[row];
#pragma unroll
      for (int nf = 0; nf < 2; ++nf)
        out[(size_t)row * NDIM + colv + nf * 32] =
            (float)acc[mf][nf][reg] * (dm * sb[nf]) + (zb[nf] * xm + bv[nf]);
    }
}

// ---------------- fallback fused 128x128 bf16 kernel (ws too small) ---------
__global__ __launch_bounds__(256, 3) void gemm_fused_kernel(
    const float* __restrict__ x, const uint32_t* __restrict__ wq,
    const float* __restrict__ scales, const float* __restrict__ zeros,
    const float* __restrict__ bias, float* __restrict__ out) {
  __shared__ __align__(16) char smem[2 * 128 * 64 * 2];
  char* As = smem;
  char* Bs = smem + 16384;

  const int tid  = threadIdx.x;
  const int lane = tid & 63;
  const int wave = tid >> 6;
  const int wm = wave >> 1, wn = wave & 1;

  const int b   = blockIdx.x;
  const int swz = (b & 7) * 344 + (b >> 3);
  const int mt  = swz / 86;
  const int nt  = swz - mt * 86;
  const int bm0 = mt * 128, bn0 = nt * 128;

  f32x4 acc[4][4];
#pragma unroll
  for (int i = 0; i < 4; ++i)
#pragma unroll
    for (int j = 0; j < 4; ++j) acc[i][j] = (f32x4){0.f, 0.f, 0.f, 0.f};

  const int base_a = ((wm * 64 + (lane & 15)) << 7) + ((lane >> 4) << 4);
  const int base_b = ((wn * 64 + (lane & 15)) << 7) + ((lane >> 4) << 4);

  float sv[4], zv[4];
#pragma unroll
  for (int it = 0; it < 4; ++it) {
    int r = bn0 + it * 32 + (tid >> 3);
    sv[it] = bf16r(scales[r]);
    zv[it] = bf16r(zeros[r]);
  }

  for (int kt = 0; kt < KDIM / 64; ++kt) {
    const int k0 = kt * 64;
    __syncthreads();
#pragma unroll
    for (int it = 0; it < 4; ++it) {
      int ch = it * 256 + tid;
      int row = ch >> 3, c8 = ch & 7;
      const float* src = x + (size_t)(bm0 + row) * KDIM + k0 + c8 * 8;
      float4 f0 = *(const float4*)src;
      float4 f1 = *(const float4*)(src + 4);
      u16x8 v;
      v[0] = f2bf(f0.x); v[1] = f2bf(f0.y); v[2] = f2bf(f0.z); v[3] = f2bf(f0.w);
      v[4] = f2bf(f1.x); v[5] = f2bf(f1.y); v[6] = f2bf(f1.z); v[7] = f2bf(f1.w);
      *(u16x8*)(As + row * 128 + c8 * 16) = v;
    }
#pragma unroll
    for (int it = 0; it < 4; ++it) {
      int ch = it * 256 + tid;
      int row = ch >> 3, kp = ch & 7;
      uint32_t w = wq[(size_t)(bn0 + row) * KP + kt * 8 + kp];
      float s = sv[it], z = zv[it];
      u16x8 v;
#pragma unroll
      for (int j = 0; j < 8; ++j) {
        float qf = (float)((w >> (4 * j)) & 0xF);
        float t  = bf16r(qf * s);
        v[j] = f2bf(t + z);
      }
      *(u16x8*)(Bs + row * 128 + kp * 16) = v;
    }
    __syncthreads();
#pragma unroll
    for (int ks = 0; ks < 2; ++ks) {
      bf16x8 af[4], bf[4];
#pragma unroll
      for (int i = 0; i < 4; ++i)
        af[i] = *(const bf16x8*)(As + base_a + i * 2048 + ks * 64);
#pragma unroll
      for (int j = 0; j < 4; ++j)
        bf[j] = *(const bf16x8*)(Bs + base_b + j * 2048 + ks * 64);
#pragma unroll
      for (int i = 0; i < 4; ++i)
#pragma unroll
        for (int j = 0; j < 4; ++j)
          acc[i][j] = __builtin_amdgcn_mfma_f32_16x16x32_bf16(af[i], bf[j],
                                                              acc[i][j], 0, 0, 0);
    }
  }

  const int colbase = bn0 + wn * 64 + (lane & 15);
  const int rowbase = bm0 + wm * 64 + ((lane >> 4) << 2);
  float bv[4];
#pragma unroll
  for (int j = 0; j < 4; ++j) bv[j] = bias[colbase + j * 16];
#pragma unroll
  for (int i = 0; i < 4; ++i) {
#pragma unroll
    for (int j = 0; j < 4; ++j) {
      size_t base = (size_t)(rowbase + i * 16) * NDIM + colbase + j * 16;
#pragma unroll
      for (int r = 0; r < 4; ++r)
        out[base + (size_t)r * NDIM] = acc[i][j][r] + bv[j];
    }
  }
}

extern "C" void kernel_launch(void* const* d_in, const int* in_sizes, int n_in,
                              void* d_out, int out_size, void* d_ws, size_t ws_size,
                              hipStream_t stream) {
  const float*    x      = (const float*)d_in[0];
  const uint32_t* wq     = (const uint32_t*)d_in[1];
  const float*    scales = (const float*)d_in[2];
  const float*    zeros  = (const float*)d_in[3];
  const float*    bias   = (const float*)d_in[4];
  float*          out    = (float*)d_out;

  const size_t offQ = 0;
  const size_t szQ  = (size_t)NDIM * KDIM;           // 45,088,768
  const size_t offX = szQ;
  const size_t szX  = (size_t)MDIM * KDIM;           // 16,777,216
  const size_t offD = offX + szX;                    // 61,865,984
  const size_t offS = offD + MDIM * sizeof(float);
  const size_t need = offS + MDIM * sizeof(float);   // ~61.9 MB

  if (ws_size >= need) {
    char*  Q8    = (char*)d_ws + offQ;
    char*  X8    = (char*)d_ws + offX;
    float* dlt   = (float*)((char*)d_ws + offD);
    float* xsm   = (float*)((char*)d_ws + offS);
    repack_q_kernel<<<(NDIM * KP) / 256, 256, 0, stream>>>(wq, (c8x8*)Q8);
    quant_x_kernel<<<MDIM, 256, 0, stream>>>(x, (c8x16*)X8, dlt, xsm);
    gemm256_i8_kernel<<<688, 512, 0, stream>>>(X8, Q8, dlt, xsm, scales, zeros,
                                               bias, out);
  } else {
    gemm_fused_kernel<<<2752, 256, 0, stream>>>(x, wq, scales, zeros, bias, out);
  }
}

// Round 10
// 232.426 us; speedup vs baseline: 1.7828x; 1.0504x over previous
//
#include <hip/hip_runtime.h>
#include <stdint.h>

#define MDIM 4096
#define KDIM 4096
#define NDIM 11008
#define KP   (KDIM/8)    // 512 packed int32 per N-row
#define NKT2 (KDIM/128)  // 32 K-tiles of BK=128 (int8 path)

typedef float  f32x4   __attribute__((ext_vector_type(4)));
typedef __bf16 bf16x8  __attribute__((ext_vector_type(8)));
typedef unsigned short u16x8 __attribute__((ext_vector_type(8)));
typedef int    i32x4   __attribute__((ext_vector_type(4)));
typedef int    i32x16  __attribute__((ext_vector_type(16)));
typedef char   c8x8    __attribute__((ext_vector_type(8)));
typedef char   c8x16   __attribute__((ext_vector_type(16)));

// RNE f32 -> bf16 bits (matches jax astype(bf16) for non-NaN inputs)
__device__ __forceinline__ unsigned short f2bf(float f) {
  uint32_t u = __builtin_bit_cast(uint32_t, f);
  u += 0x7FFFu + ((u >> 16) & 1u);
  return (unsigned short)(u >> 16);
}
__device__ __forceinline__ float bf2f(unsigned short h) {
  return __builtin_bit_cast(float, (uint32_t)h << 16);
}
__device__ __forceinline__ float bf16r(float f) { return bf2f(f2bf(f)); }

// async global -> LDS, 16B per lane, wave-uniform LDS base + lane*16
__device__ __forceinline__ void lds16(const void* g, void* l) {
  __builtin_amdgcn_global_load_lds(
      (const __attribute__((address_space(1))) unsigned int*)g,
      (__attribute__((address_space(3))) unsigned int*)l, 16, 0, 0);
}

// ---------------- pre-pass 1: unpack int4 words -> int8 Q8[N][K] ------------
__global__ __launch_bounds__(256) void repack_q_kernel(
    const uint32_t* __restrict__ wq, c8x8* __restrict__ Q8) {
  int idx = blockIdx.x * 256 + threadIdx.x;   // [0, N*KP)
  uint32_t w = wq[idx];
  c8x8 v;
#pragma unroll
  for (int j = 0; j < 8; ++j) v[j] = (char)((w >> (4 * j)) & 0xF);
  Q8[idx] = v;
}

// ---------------- pre-pass 2: x f32 -> per-row int8 + delta + exact bf16 sum
// one block per row. x8 = round(bf16(x)/Delta), Delta = rowmax|bf16(x)|/127.
// xsum = exact f32 sum of bf16(x) (feeds the z-term with NO quant error).
__global__ __launch_bounds__(256) void quant_x_kernel(
    const float* __restrict__ x, c8x16* __restrict__ X8,
    float* __restrict__ delta, float* __restrict__ xsum) {
  __shared__ float red[256];
  const int row = blockIdx.x, t = threadIdx.x;
  const float4* xr = (const float4*)(x + (size_t)row * KDIM);
  float xb[16];
#pragma unroll
  for (int i = 0; i < 4; ++i) {
    float4 f = xr[t * 4 + i];
    xb[i * 4 + 0] = bf16r(f.x); xb[i * 4 + 1] = bf16r(f.y);
    xb[i * 4 + 2] = bf16r(f.z); xb[i * 4 + 3] = bf16r(f.w);
  }
  float mx = 0.f, sm = 0.f;
#pragma unroll
  for (int j = 0; j < 16; ++j) { mx = fmaxf(mx, fabsf(xb[j])); sm += xb[j]; }
  red[t] = mx; __syncthreads();
  for (int o = 128; o > 0; o >>= 1) {
    if (t < o) red[t] = fmaxf(red[t], red[t + o]);
    __syncthreads();
  }
  const float rmx = red[0];
  __syncthreads();
  red[t] = sm; __syncthreads();
  for (int o = 128; o > 0; o >>= 1) {
    if (t < o) red[t] += red[t + o];
    __syncthreads();
  }
  const float rsm = red[0];
  const float inv = (rmx > 0.f) ? 127.0f / rmx : 0.f;
  if (t == 0) {
    delta[row] = (rmx > 0.f) ? rmx / 127.0f : 0.f;
    xsum[row]  = rsm;
  }
  c8x16 q;
#pragma unroll
  for (int j = 0; j < 16; ++j) q[j] = (char)__float2int_rn(xb[j] * inv);
  X8[(size_t)row * 256 + t] = q;
}

// ---------------- main GEMM: 256x256, BK=128, 8 waves, i8 32x32x32, 4-phase -
// Round-9 frame with the chunk-permutation selector changed b1 -> b3 (both
// sides): r9's read bank-quad bits were {r15&1, b1^s, hk^sub} -> 1.69e7
// conflicts; r6/r7/r8's proven-ZERO pattern was {r15&1, b3^s, hk^sub}. Only
// the selector bit differs — this round makes the i8 read pattern
// bit-identical to the proven one.
// Store: LDS position c of row r holds global 16B chunk c ^ (b3(r)<<1) ^ sub
// (sub = odd-subtile flag), realized by per-lane global source offset
// (linear LDS dest, rule #21). Read: c1 = b3^s, c0 = hk^sub — returns
// exactly chunk (s,hk); XOR involution verified.
__global__ __launch_bounds__(512, 2) void gemm256_i8_kernel(
    const char* __restrict__ A8, const char* __restrict__ Q8,
    const float* __restrict__ delta, const float* __restrict__ xsum,
    const float* __restrict__ scales, const float* __restrict__ zeros,
    const float* __restrict__ bias, float* __restrict__ out) {
  __shared__ __align__(16) char smem[131072];

  const int tid  = threadIdx.x;
  const int lane = tid & 63;
  const int wave = tid >> 6;     // 0..7
  const int wm   = wave >> 2;    // 0..1 : M half (128 rows)
  const int wn   = wave & 3;     // 0..3 : N quarter (64 cols)

  // XCD-aware bijective swizzle: 688 = 8 * 86 blocks.
  const int b   = blockIdx.x;
  const int swz = (b & 7) * 86 + (b >> 3);
  const int mt  = swz / 43;
  const int nt  = swz - mt * 43;
  const int bm0 = mt * 256, bn0 = nt * 256;

  // staging geometry: lane l writes subtile bytes [l*16, l*16+16):
  // row srow = l>>2, stored position schunk = l&3; source global chunk =
  // schunk ^ (b3(srow)<<1) (^1 for the odd subtile).
  const int srow   = lane >> 2;
  const int schunk = lane & 3;
  const int perm0  = schunk ^ (((srow >> 3) & 1) << 1);
  const int perm1  = perm0 ^ 1;
  const char* aR  = A8 + (size_t)(bm0 + wave * 32 + srow) * KDIM + perm0 * 16;
  const char* aR2 = A8 + (size_t)(bm0 + wave * 32 + 16 + srow) * KDIM + perm1 * 16;
  const char* bR  = Q8 + (size_t)(bn0 + wave * 32 + srow) * KDIM + perm0 * 16;
  const char* bR2 = Q8 + (size_t)(bn0 + wave * 32 + 16 + srow) * KDIM + perm1 * 16;

  // fragment read offset for ks32 step s=0 (rd0) / s=1 (rd1 = rd0^32).
  // bank-quad bits: {bit6 = r15&1, bit5 = b3^s, bit4 = hk^sub} — the
  // r6-proven zero-conflict pattern.
  const int r31 = lane & 31;
  const int sub = r31 >> 4;
  const int r15 = r31 & 15;
  const int hk  = lane >> 5;
  const int rd0 = sub * 1024 + r15 * 64 + ((hk ^ sub) << 4) + ((r15 & 8) << 2);
  const int rd1 = rd0 ^ 32;

  const int aoffc = wm * 8192;          // wm*8 subtiles (128 rows)
  const int boffc = 65536 + wn * 4096;  // B ring + wn*4 subtiles (64 rows)

  i32x16 acc[4][2];
#pragma unroll
  for (int i = 0; i < 4; ++i)
#pragma unroll
    for (int j = 0; j < 2; ++j)
#pragma unroll
      for (int r = 0; r < 16; ++r) acc[i][j][r] = 0;

  i32x4 Af[4], Bf[2];

#define STAGE_A(tile, h, slot)                                              \
  do {                                                                      \
    const size_t ko_ = (size_t)((tile) * 128 + (h) * 64);                   \
    char* d_ = smem + ((slot) << 14) + wave * 2048;                         \
    lds16(aR + ko_, d_);                                                    \
    lds16(aR2 + ko_, d_ + 1024);                                            \
  } while (0)

#define STAGE_B(tile, h, slot)                                              \
  do {                                                                      \
    const size_t ko_ = (size_t)((tile) * 128 + (h) * 64);                   \
    char* d_ = smem + 65536 + ((slot) << 14) + wave * 2048;                 \
    lds16(bR + ko_, d_);                                                    \
    lds16(bR2 + ko_, d_ + 1024);                                            \
  } while (0)

#define READ6(slotbase, S)                                                  \
  do {                                                                      \
    const int ro_ = (S) ? rd1 : rd0;                                        \
    _Pragma("unroll") for (int mf = 0; mf < 4; ++mf)                        \
        Af[mf] = *(const i32x4*)(smem + aoffc + (slotbase) +                \
                                 mf * 2048 + ro_);                          \
    _Pragma("unroll") for (int nf = 0; nf < 2; ++nf)                        \
        Bf[nf] = *(const i32x4*)(smem + boffc + (slotbase) +                \
                                 nf * 2048 + ro_);                          \
  } while (0)

#define MFMA8()                                                             \
  __builtin_amdgcn_s_setprio(1);                                            \
  _Pragma("unroll") for (int mf = 0; mf < 4; ++mf)                          \
      _Pragma("unroll") for (int nf = 0; nf < 2; ++nf)                      \
          acc[mf][nf] = __builtin_amdgcn_mfma_i32_32x32x32_i8(              \
              Af[mf], Bf[nf], acc[mf][nf], 0, 0, 0);                        \
  __builtin_amdgcn_s_setprio(0);

#define BAR                                                                 \
  __builtin_amdgcn_s_barrier();                                             \
  __builtin_amdgcn_sched_barrier(0);

#define VMWAIT(N) asm volatile("s_waitcnt vmcnt(" #N ")" ::: "memory")

  // 4 phases/K-tile: (h0,s0),(h0,s1),(h1,s0),(h1,s1). Staging: p0 A(T+1,h1),
  // p1 B(T+1,h1) + VM, p2 A(T+2,h0)->S0s (recycle), p3 B(T+2,h0) + VM.
  // Identical slot/vmcnt schedule to rounds 8/9 (traced + passing).
#define TILE(T, S0s, S1s, SN1s, NSTG, VM1STMT, VM3STMT)                     \
  do {                                                                      \
    READ6((S0s) << 14, 0);                                                  \
    if ((NSTG) >= 1) STAGE_A((T) + 1, 1, SN1s);                             \
    BAR; MFMA8(); BAR;                                                      \
    READ6((S0s) << 14, 1);                                                  \
    if ((NSTG) >= 2) STAGE_B((T) + 1, 1, SN1s);                             \
    VM1STMT;                                                                \
    BAR; MFMA8(); BAR;                                                      \
    READ6((S1s) << 14, 0);                                                  \
    if ((NSTG) >= 3) STAGE_A((T) + 2, 0, S0s);                              \
    BAR; MFMA8(); BAR;                                                      \
    READ6((S1s) << 14, 1);                                                  \
    if ((NSTG) >= 4) STAGE_B((T) + 2, 0, S0s);                              \
    VM3STMT;                                                                \
    BAR; MFMA8(); BAR;                                                      \
  } while (0)

  // prologue: (0,h0)->s0, (0,h1)->s1, (1,h0)->s2 = 12 loads; retire first 4
  STAGE_A(0, 0, 0);
  STAGE_B(0, 0, 0);
  STAGE_A(0, 1, 1);
  STAGE_B(0, 1, 1);
  STAGE_A(1, 0, 2);
  STAGE_B(1, 0, 2);
  VMWAIT(8);
  BAR;

  for (int tt = 0; tt < 30; tt += 2) {
    TILE(tt,     0, 1, 3, 4, VMWAIT(8), VMWAIT(8));
    TILE(tt + 1, 2, 3, 1, 4, VMWAIT(8), VMWAIT(8));
  }
  // T=30: stage only (31,h1); T=31: no staging, drain
  TILE(30, 0, 1, 3, 2, VMWAIT(8), VMWAIT(4));
  TILE(31, 2, 3, 1, 0, VMWAIT(0), (void)0);

#undef TILE
#undef VMWAIT
#undef BAR
#undef MFMA8
#undef READ6
#undef STAGE_B
#undef STAGE_A

  // epilogue: C/D 32x32 layout col=lane&31, row=(reg&3)+8*(reg>>2)+4*(lane>>5)
  // out = acc * (Delta_m * bf16(s_n)) + bf16(z_n) * xsum_m + bias_n
  const int colv = bn0 + wn * 64 + (lane & 31);
  const int rowb = bm0 + wm * 128 + ((lane >> 5) << 2);
  float sb[2], zb[2], bv[2];
#pragma unroll
  for (int nf = 0; nf < 2; ++nf) {
    sb[nf] = bf16r(scales[colv + nf * 32]);
    zb[nf] = bf16r(zeros[colv + nf * 32]);
    bv[nf] = bias[colv + nf * 32];
  }
#pragma unroll
  for (int mf = 0; mf < 4; ++mf)
#pragma unroll
    for (int reg = 0; reg < 16; ++reg) {
      const int row = rowb + mf * 32 + (reg & 3) + ((reg >> 2) << 3);
      const float dm = delta[row];
      const float xm = xsum[row];
#pragma unroll
      for (int nf = 0; nf < 2; ++nf)
        out[(size_t)row * NDIM + colv + nf * 32] =
            (float)acc[mf][nf][reg] * (dm * sb[nf]) + (zb[nf] * xm + bv[nf]);
    }
}

// ---------------- fallback fused 128x128 bf16 kernel (ws too small) ---------
__global__ __launch_bounds__(256, 3) void gemm_fused_kernel(
    const float* __restrict__ x, const uint32_t* __restrict__ wq,
    const float* __restrict__ scales, const float* __restrict__ zeros,
    const float* __restrict__ bias, float* __restrict__ out) {
  __shared__ __align__(16) char smem[2 * 128 * 64 * 2];
  char* As = smem;
  char* Bs = smem + 16384;

  const int tid  = threadIdx.x;
  const int lane = tid & 63;
  const int wave = tid >> 6;
  const int wm = wave >> 1, wn = wave & 1;

  const int b   = blockIdx.x;
  const int swz = (b & 7) * 344 + (b >> 3);
  const int mt  = swz / 86;
  const int nt  = swz - mt * 86;
  const int bm0 = mt * 128, bn0 = nt * 128;

  f32x4 acc[4][4];
#pragma unroll
  for (int i = 0; i < 4; ++i)
#pragma unroll
    for (int j = 0; j < 4; ++j) acc[i][j] = (f32x4){0.f, 0.f, 0.f, 0.f};

  const int base_a = ((wm * 64 + (lane & 15)) << 7) + ((lane >> 4) << 4);
  const int base_b = ((wn * 64 + (lane & 15)) << 7) + ((lane >> 4) << 4);

  float sv[4], zv[4];
#pragma unroll
  for (int it = 0; it < 4; ++it) {
    int r = bn0 + it * 32 + (tid >> 3);
    sv[it] = bf16r(scales[r]);
    zv[it] = bf16r(zeros[r]);
  }

  for (int kt = 0; kt < KDIM / 64; ++kt) {
    const int k0 = kt * 64;
    __syncthreads();
#pragma unroll
    for (int it = 0; it < 4; ++it) {
      int ch = it * 256 + tid;
      int row = ch >> 3, c8 = ch & 7;
      const float* src = x + (size_t)(bm0 + row) * KDIM + k0 + c8 * 8;
      float4 f0 = *(const float4*)src;
      float4 f1 = *(const float4*)(src + 4);
      u16x8 v;
      v[0] = f2bf(f0.x); v[1] = f2bf(f0.y); v[2] = f2bf(f0.z); v[3] = f2bf(f0.w);
      v[4] = f2bf(f1.x); v[5] = f2bf(f1.y); v[6] = f2bf(f1.z); v[7] = f2bf(f1.w);
      *(u16x8*)(As + row * 128 + c8 * 16) = v;
    }
#pragma unroll
    for (int it = 0; it < 4; ++it) {
      int ch = it * 256 + tid;
      int row = ch >> 3, kp = ch & 7;
      uint32_t w = wq[(size_t)(bn0 + row) * KP + kt * 8 + kp];
      float s = sv[it], z = zv[it];
      u16x8 v;
#pragma unroll
      for (int j = 0; j < 8; ++j) {
        float qf = (float)((w >> (4 * j)) & 0xF);
        float t  = bf16r(qf * s);
        v[j] = f2bf(t + z);
      }
      *(u16x8*)(Bs + row * 128 + kp * 16) = v;
    }
    __syncthreads();
#pragma unroll
    for (int ks = 0; ks < 2; ++ks) {
      bf16x8 af[4], bf[4];
#pragma unroll
      for (int i = 0; i < 4; ++i)
        af[i] = *(const bf16x8*)(As + base_a + i * 2048 + ks * 64);
#pragma unroll
      for (int j = 0; j < 4; ++j)
        bf[j] = *(const bf16x8*)(Bs + base_b + j * 2048 + ks * 64);
#pragma unroll
      for (int i = 0; i < 4; ++i)
#pragma unroll
        for (int j = 0; j < 4; ++j)
          acc[i][j] = __builtin_amdgcn_mfma_f32_16x16x32_bf16(af[i], bf[j],
                                                              acc[i][j], 0, 0, 0);
    }
  }

  const int colbase = bn0 + wn * 64 + (lane & 15);
  const int rowbase = bm0 + wm * 64 + ((lane >> 4) << 2);
  float bv[4];
#pragma unroll
  for (int j = 0; j < 4; ++j) bv[j] = bias[colbase + j * 16];
#pragma unroll
  for (int i = 0; i < 4; ++i) {
#pragma unroll
    for (int j = 0; j < 4; ++j) {
      size_t base = (size_t)(rowbase + i * 16) * NDIM + colbase + j * 16;
#pragma unroll
      for (int r = 0; r < 4; ++r)
        out[base + (size_t)r * NDIM] = acc[i][j][r] + bv[j];
    }
  }
}

extern "C" void kernel_launch(void* const* d_in, const int* in_sizes, int n_in,
                              void* d_out, int out_size, void* d_ws, size_t ws_size,
                              hipStream_t stream) {
  const float*    x      = (const float*)d_in[0];
  const uint32_t* wq     = (const uint32_t*)d_in[1];
  const float*    scales = (const float*)d_in[2];
  const float*    zeros  = (const float*)d_in[3];
  const float*    bias   = (const float*)d_in[4];
  float*          out    = (float*)d_out;

  const size_t offQ = 0;
  const size_t szQ  = (size_t)NDIM * KDIM;           // 45,088,768
  const size_t offX = szQ;
  const size_t szX  = (size_t)MDIM * KDIM;           // 16,777,216
  const size_t offD = offX + szX;                    // 61,865,984
  const size_t offS = offD + MDIM * sizeof(float);
  const size_t need = offS + MDIM * sizeof(float);   // ~61.9 MB

  if (ws_size >= need) {
    char*  Q8    = (char*)d_ws + offQ;
    char*  X8    = (char*)d_ws + offX;
    float* dlt   = (float*)((char*)d_ws + offD);
    float* xsm   = (float*)((char*)d_ws + offS);
    repack_q_kernel<<<(NDIM * KP) / 256, 256, 0, stream>>>(wq, (c8x8*)Q8);
    quant_x_kernel<<<MDIM, 256, 0, stream>>>(x, (c8x16*)X8, dlt, xsm);
    gemm256_i8_kernel<<<688, 512, 0, stream>>>(X8, Q8, dlt, xsm, scales, zeros,
                                               bias, out);
  } else {
    gemm_fused_kernel<<<2752, 256, 0, stream>>>(x, wq, scales, zeros, bias, out);
  }
}